// Round 1
// 788.421 us; speedup vs baseline: 1.2178x; 1.2178x over previous
//
#include <hip/hip_runtime.h>
#include <stdint.h>

#define DM  1024
#define NB  8
#define LQ  4096
#define SSQ 4096
#define NH  16
#define HE  64
#define UU  40
#define NS  8
#define SPL (SSQ/NS)

using u16 = unsigned short;
using u32 = unsigned int;

typedef __bf16 bf16x8 __attribute__((ext_vector_type(8)));
typedef float  f32x4  __attribute__((ext_vector_type(4)));

#define AS1 __attribute__((address_space(1)))
#define AS3 __attribute__((address_space(3)))

__device__ __forceinline__ void gld_lds16(const void* g, void* l) {
  __builtin_amdgcn_global_load_lds((const AS1 u32*)g, (AS3 u32*)l, 16, 0, 0);
}

__device__ __forceinline__ u16 f2bf(float x) {
  u32 u = __float_as_uint(x);
  u32 r = (u + 0x7fffu + ((u >> 16) & 1u)) >> 16;   // RNE
  return (u16)r;
}

// ---------------- fp32 -> bf16 convert ------------------------------------
__global__ __launch_bounds__(256)
void conv_bf16(const float* __restrict__ src, u16* __restrict__ dst, long n) {
  long i = ((long)blockIdx.x * 256 + threadIdx.x) * 8;
  if (i >= n) return;
  float4 a = *(const float4*)(src + i);
  float4 b = *(const float4*)(src + i + 4);
  union { u16 h[8]; uint4 v; } pk;
  pk.h[0]=f2bf(a.x); pk.h[1]=f2bf(a.y); pk.h[2]=f2bf(a.z); pk.h[3]=f2bf(a.w);
  pk.h[4]=f2bf(b.x); pk.h[5]=f2bf(b.y); pk.h[6]=f2bf(b.z); pk.h[7]=f2bf(b.w);
  *(uint4*)(dst + i) = pk.v;
}

// gather sampled query rows -> contiguous [NB*UU][DM] bf16
__global__ __launch_bounds__(128)
void gather_q_bf16(const float* __restrict__ q, const int* __restrict__ sidx,
                   u16* __restrict__ dst) {
  int r = blockIdx.x;                  // 0..NB*UU-1
  int b = r / UU, u = r - b*UU;
  long srow = ((long)b*LQ + sidx[u]) * DM;
  int c = threadIdx.x * 8;
  float4 a = *(const float4*)(q + srow + c);
  float4 bb = *(const float4*)(q + srow + c + 4);
  union { u16 h[8]; uint4 v; } pk;
  pk.h[0]=f2bf(a.x); pk.h[1]=f2bf(a.y); pk.h[2]=f2bf(a.z); pk.h[3]=f2bf(a.w);
  pk.h[4]=f2bf(bb.x); pk.h[5]=f2bf(bb.y); pk.h[6]=f2bf(bb.z); pk.h[7]=f2bf(bb.w);
  *(uint4*)(dst + (long)r*DM + c) = pk.v;
}

// ---------------- bf16 MFMA GEMM: C[r,c] = sum_k A[r,k]*B[c,k] + bias -----
// 128x128 tile, BK=32, 256 threads (4 waves, each 64x64), 16x16x32 mfma.
// BIAS_ROW: bias indexed by output row (used for transposed-V GEMM).
// ldo: output leading stride (elements).
template<bool OUT_BF16, bool BIAS_ROW>
__global__ __launch_bounds__(256)
void gemm_mfma(const u16* __restrict__ Xb, const u16* __restrict__ Wb,
               const float* __restrict__ bias, void* __restrict__ outp,
               int R, long ldo)
{
  __shared__ u16 As[128*40];     // 10240 B
  __shared__ u16 Bs[128*40];
  const int t = threadIdx.x;
  const int l = t & 63;
  const int w = t >> 6;
  const int r0 = blockIdx.x * 128;
  const int o0 = blockIdx.y * 128;

  // staging: 1280 16-B chunks per K-step (A:640, B:640 -- 5 per row, chunk 4 = pad)
  const u16* gsrc[5];
  char* ldst[5];
#pragma unroll
  for (int i = 0; i < 5; i++) {
    int c  = i*256 + t;           // per-thread chunk id
    int cb = i*256 + w*64;        // wave-uniform chunk base (640 % 64 == 0 -> same side)
    bool a = (cb < 640);
    int cc2 = a ? c : (c - 640);
    int row = cc2 / 5, col = cc2 % 5; if (col > 3) col = 0;  // pad chunk loads dup data
    if (a) {
      int rr = r0 + row; if (rr > R-1) rr = R-1;
      gsrc[i] = Xb + (long)rr * DM + col*8;
      ldst[i] = (char*)As + cb*16;
    } else {
      gsrc[i] = Wb + (long)(o0 + row) * DM + col*8;
      ldst[i] = (char*)Bs + (cb - 640)*16;
    }
  }

  f32x4 acc[4][4];
  const f32x4 z4 = {0.f, 0.f, 0.f, 0.f};
#pragma unroll
  for (int mt = 0; mt < 4; mt++)
#pragma unroll
    for (int nt = 0; nt < 4; nt++) acc[mt][nt] = z4;

  const int rw = (w >> 1) * 64;
  const int cw = (w & 1) * 64;
  const int fr = l & 15;
  const int fk = (l >> 4) * 8;

  for (int k0 = 0; k0 < DM; k0 += 32) {
    __syncthreads();
#pragma unroll
    for (int i = 0; i < 5; i++)
      gld_lds16(gsrc[i] + k0, ldst[i]);
    __syncthreads();

    bf16x8 af[4], bf[4];
#pragma unroll
    for (int mt = 0; mt < 4; mt++)
      af[mt] = *(const bf16x8*)&As[(rw + mt*16 + fr)*40 + fk];
#pragma unroll
    for (int nt = 0; nt < 4; nt++)
      bf[nt] = *(const bf16x8*)&Bs[(cw + nt*16 + fr)*40 + fk];
#pragma unroll
    for (int mt = 0; mt < 4; mt++)
#pragma unroll
      for (int nt = 0; nt < 4; nt++)
        acc[mt][nt] = __builtin_amdgcn_mfma_f32_16x16x32_bf16(af[mt], bf[nt], acc[mt][nt], 0, 0, 0);
  }

  // epilogue: D elem (reg i) = C[row=(l>>4)*4+i][col=l&15] within each 16x16 tile
  const int colBase = o0 + cw + (l & 15);
  const int rowBase = r0 + rw + ((l >> 4) << 2);
#pragma unroll
  for (int nt = 0; nt < 4; nt++) {
    float bvc = BIAS_ROW ? 0.f : bias[colBase + nt*16];
#pragma unroll
    for (int mt = 0; mt < 4; mt++) {
#pragma unroll
      for (int i2 = 0; i2 < 4; i2++) {
        int r = rowBase + mt*16 + i2;
        if (r < R) {
          float v = acc[mt][nt][i2] + (BIAS_ROW ? bias[r] : bvc);
          long o = (long)r*ldo + colBase + nt*16;
          if (OUT_BF16) ((u16*)outp)[o] = f2bf(v);
          else          ((float*)outp)[o] = v;
        }
      }
    }
  }
}

// ---------------- kernel A: MFMA scores -> per-split softmax stats --------
// grid (NH, NB, NS); 4 waves, each owns 128 s. No score write at all.
__global__ __launch_bounds__(256)
void attn_stats(const u16* __restrict__ Qs16, const u16* __restrict__ Kb,
                float* __restrict__ STp)
{
  const int h = blockIdx.x, b = blockIdx.y, z = blockIdx.z;
  const int t = threadIdx.x, l = t & 63, w = t >> 6;
  __shared__ float sm4[4][48], sl4[4][48];

  bf16x8 qf[3][2];
#pragma unroll
  for (int mt = 0; mt < 3; mt++) {
    int u = mt*16 + (l & 15); if (u >= UU) u = UU-1;
    const u16* qrow = Qs16 + ((long)b*UU + u)*DM + h*HE + ((l>>4)*8);
    qf[mt][0] = *(const bf16x8*)qrow;
    qf[mt][1] = *(const bf16x8*)(qrow + 32);
  }
  float m_[12], l_[12];
#pragma unroll
  for (int i = 0; i < 12; i++) { m_[i] = -1e30f; l_[i] = 0.f; }

  const f32x4 z4 = {0.f,0.f,0.f,0.f};
  const int sbase = z*SPL + w*128;
  for (int tt = 0; tt < 8; tt++) {
    const int s0 = sbase + tt*16;
    const u16* krow = Kb + ((long)(b*SSQ + s0 + (l & 15)))*DM + h*HE + ((l>>4)*8);
    bf16x8 kf0 = *(const bf16x8*)krow;
    bf16x8 kf1 = *(const bf16x8*)(krow + 32);
    f32x4 as[3];
#pragma unroll
    for (int mt = 0; mt < 3; mt++) {
      as[mt] = __builtin_amdgcn_mfma_f32_16x16x32_bf16(qf[mt][0], kf0, z4, 0, 0, 0);
      as[mt] = __builtin_amdgcn_mfma_f32_16x16x32_bf16(qf[mt][1], kf1, as[mt], 0, 0, 0);
    }
#pragma unroll
    for (int mt = 0; mt < 3; mt++)
#pragma unroll
      for (int i2 = 0; i2 < 4; i2++) {
        int idx = mt*4 + i2;
        float x = as[mt][i2] * 0.03125f;
        float mn = fmaxf(m_[idx], x);
        l_[idx] = l_[idx]*__expf(m_[idx]-mn) + __expf(x-mn);
        m_[idx] = mn;
      }
  }
#pragma unroll
  for (int off = 1; off < 16; off <<= 1)
#pragma unroll
    for (int idx = 0; idx < 12; idx++) {
      float m2 = __shfl_xor(m_[idx], off, 64);
      float l2 = __shfl_xor(l_[idx], off, 64);
      float mn = fmaxf(m_[idx], m2);
      l_[idx] = l_[idx]*__expf(m_[idx]-mn) + l2*__expf(m2-mn);
      m_[idx] = mn;
    }
  if ((l & 15) == 0) {
#pragma unroll
    for (int idx = 0; idx < 12; idx++) {
      int u = (idx>>2)*16 + ((l>>4)<<2) + (idx&3);
      sm4[w][u] = m_[idx]; sl4[w][u] = l_[idx];
    }
  }
  __syncthreads();
  if (t < UU) {
    float M = -1e30f, L = 0.f;
#pragma unroll
    for (int wv = 0; wv < 4; wv++) {
      float m2 = sm4[wv][t], l2 = sl4[wv][t];
      float mn = fmaxf(M, m2);
      L = L*__expf(M-mn) + l2*__expf(m2-mn);
      M = mn;
    }
    long p = (((long)(b*NH + h)*UU + t)*NS + z)*2;
    STp[p] = M; STp[p+1] = L;
  }
}

// ---------------- merge per-split (m,l) -> global (M,L) -------------------
__global__ __launch_bounds__(256)
void merge_stats(const float* __restrict__ STp, float* __restrict__ ST) {
  int idx = blockIdx.x*256 + threadIdx.x;
  if (idx >= NB*NH*UU) return;
  float M = -1e30f;
#pragma unroll
  for (int z = 0; z < NS; z++) M = fmaxf(M, STp[((long)idx*NS+z)*2]);
  float L = 0.f;
#pragma unroll
  for (int z = 0; z < NS; z++)
    L += STp[((long)idx*NS+z)*2+1] * __expf(STp[((long)idx*NS+z)*2] - M);
  ST[idx*2] = M; ST[idx*2+1] = L;
}

// ---------------- kernel B: recompute scores, write attn once, MFMA PV ----
__global__ __launch_bounds__(256, 2)
void attn_pv(const u16* __restrict__ Qs16, const u16* __restrict__ Kb,
             const u16* __restrict__ VTb, const float* __restrict__ ST,
             float* __restrict__ attn, float* __restrict__ ohp)
{
  const int h = blockIdx.x, b = blockIdx.y, z = blockIdx.z;
  const int t = threadIdx.x, l = t & 63, w = t >> 6;
  const long LVT = (long)NB*SSQ;

  __shared__ u16   Plds[4][48*40];      // per-wave P tile, row pad 40 u16
  __shared__ float sM[48], sLi[48];
  __shared__ float red[48][68];         // block-level out^T reduce [u][e]

  if (t < 48) {
    if (t < UU) {
      long p = ((long)(b*NH+h)*UU + t)*2;
      sM[t] = ST[p]; sLi[t] = 1.f / ST[p+1];
    } else { sM[t] = 0.f; sLi[t] = 0.f; }
  }
  __syncthreads();

  float Mr[12], Lir[12];
#pragma unroll
  for (int mt = 0; mt < 3; mt++)
#pragma unroll
    for (int i2 = 0; i2 < 4; i2++) {
      int u = mt*16 + ((l>>4)<<2) + i2;
      Mr[mt*4+i2] = sM[u]; Lir[mt*4+i2] = sLi[u];
    }

  bf16x8 qf[3][2];
#pragma unroll
  for (int mt = 0; mt < 3; mt++) {
    int u = mt*16 + (l & 15); if (u >= UU) u = UU-1;
    const u16* qrow = Qs16 + ((long)b*UU + u)*DM + h*HE + ((l>>4)*8);
    qf[mt][0] = *(const bf16x8*)qrow;
    qf[mt][1] = *(const bf16x8*)(qrow + 32);
  }

  f32x4 acc_pv[4][3];
  const f32x4 z4 = {0.f,0.f,0.f,0.f};
#pragma unroll
  for (int et = 0; et < 4; et++)
#pragma unroll
    for (int nt = 0; nt < 3; nt++) acc_pv[et][nt] = z4;

  const int sbase = z*SPL + w*128;
  for (int tt = 0; tt < 4; tt++) {
    const int s0 = sbase + tt*32;
    bf16x8 vf[4];
#pragma unroll
    for (int et = 0; et < 4; et++)
      vf[et] = *(const bf16x8*)(VTb + (long)(h*HE + et*16 + (l&15))*LVT
                                    + (long)b*SSQ + s0 + ((l>>4)*8));
    bf16x8 kf[2][2];
#pragma unroll
    for (int st = 0; st < 2; st++) {
      const u16* krow = Kb + ((long)(b*SSQ + s0 + st*16 + (l & 15)))*DM + h*HE + ((l>>4)*8);
      kf[st][0] = *(const bf16x8*)krow;
      kf[st][1] = *(const bf16x8*)(krow + 32);
    }
#pragma unroll
    for (int st = 0; st < 2; st++) {
      f32x4 as[3];
#pragma unroll
      for (int mt = 0; mt < 3; mt++) {
        as[mt] = __builtin_amdgcn_mfma_f32_16x16x32_bf16(qf[mt][0], kf[st][0], z4, 0, 0, 0);
        as[mt] = __builtin_amdgcn_mfma_f32_16x16x32_bf16(qf[mt][1], kf[st][1], as[mt], 0, 0, 0);
      }
#pragma unroll
      for (int mt = 0; mt < 3; mt++)
#pragma unroll
        for (int i2 = 0; i2 < 4; i2++) {
          int idx = mt*4 + i2;
          int u = mt*16 + ((l>>4)<<2) + i2;
          float p = __expf(as[mt][i2]*0.03125f - Mr[idx]) * Lir[idx];
          if (u < UU)
            attn[((long)((b*NH+h)*UU + u))*SSQ + s0 + st*16 + (l & 15)] = p;
          Plds[w][u*40 + st*16 + (l & 15)] = f2bf(p);
        }
    }
#pragma unroll
    for (int nt = 0; nt < 3; nt++) {
      bf16x8 pb = *(const bf16x8*)&Plds[w][(nt*16 + (l & 15))*40 + ((l>>4)*8)];
#pragma unroll
      for (int et = 0; et < 4; et++)
        acc_pv[et][nt] = __builtin_amdgcn_mfma_f32_16x16x32_bf16(vf[et], pb, acc_pv[et][nt], 0, 0, 0);
    }
  }

  __syncthreads();
  for (int wv = 0; wv < 4; wv++) {
    if (w == wv) {
#pragma unroll
      for (int et = 0; et < 4; et++)
#pragma unroll
        for (int nt = 0; nt < 3; nt++)
#pragma unroll
          for (int i2 = 0; i2 < 4; i2++) {
            int u = nt*16 + (l & 15);
            int e = et*16 + ((l>>4)<<2) + i2;
            if (wv == 0) red[u][e]  = acc_pv[et][nt][i2];
            else         red[u][e] += acc_pv[et][nt][i2];
          }
    }
    __syncthreads();
  }
  for (int idx = t; idx < UU*64; idx += 256) {
    int u = idx >> 6, e = idx & 63;
    ohp[(long)z*((long)NB*UU*DM) + ((long)b*UU + u)*DM + h*HE + e] = red[u][e];
  }
}

// ---------------- reduce PV partials -> bf16 OH ---------------------------
__global__ __launch_bounds__(256)
void reduce_oh(const float* __restrict__ ohp, u16* __restrict__ ohb) {
  long i = (long)blockIdx.x*256 + threadIdx.x;
  const long n = (long)NB*UU*DM;
  if (i >= n) return;
  float s = 0.f;
#pragma unroll
  for (int z = 0; z < NS; z++) s += ohp[(long)z*n + i];
  ohb[i] = f2bf(s);
}

extern "C" void kernel_launch(void* const* d_in, const int* in_sizes, int n_in,
                              void* d_out, int out_size, void* d_ws, size_t ws_size,
                              hipStream_t stream)
{
  const float* queries = (const float*)d_in[0];
  const float* keys    = (const float*)d_in[1];
  const float* values  = (const float*)d_in[2];
  const float* Wq = (const float*)d_in[3];
  const float* bq = (const float*)d_in[4];
  const float* Wk = (const float*)d_in[5];
  const float* bk = (const float*)d_in[6];
  const float* Wv = (const float*)d_in[7];
  const float* bv = (const float*)d_in[8];
  const float* Wo = (const float*)d_in[9];
  const float* bo = (const float*)d_in[10];
  const int* sidx = (const int*)d_in[11];

  float* out_main = (float*)d_out;
  float* attn     = out_main + (long)NB*UU*DM;

  const long kvE = (long)NB*SSQ*DM;         // 33,554,432
  const size_t wB = (size_t)DM*DM*2;        // one bf16 weight

  char* ws = (char*)d_ws;
  u16*  Xst = (u16*)ws;                      ws += (size_t)kvE*2;   // bf16 staged input
  u16*  Kbf = (u16*)ws;                      ws += (size_t)kvE*2;   // K bf16 [b*S+s][DM]
  u16*  VTb = (u16*)ws;                      ws += (size_t)kvE*2;   // V^T bf16 [o][b*S+s]
  u16*  Wkb = (u16*)ws;                      ws += wB;
  u16*  Wvb = (u16*)ws;                      ws += wB;
  u16*  Wqb = (u16*)ws;                      ws += wB;
  u16*  Wob = (u16*)ws;                      ws += wB;
  u16*  Qgb = (u16*)ws;                      ws += (size_t)NB*UU*DM*2;
  u16*  Qs16= (u16*)ws;                      ws += (size_t)NB*UU*DM*2;
  u16*  OHb = (u16*)ws;                      ws += (size_t)NB*UU*DM*2;
  float* ohp = (float*)ws;                   ws += (size_t)NS*NB*UU*DM*4;
  float* STp = (float*)ws;                   ws += (size_t)NB*NH*UU*NS*2*4;
  float* ST  = (float*)ws;

  dim3 blk(256);
  const long wN = (long)DM*DM;
  dim3 gconvW((wN/8 + 255)/256);
  dim3 gconvX((kvE/8 + 255)/256);
  dim3 gkv(NB*SSQ/128, DM/128);     // (256, 8)  K GEMM
  dim3 gvt(DM/128, NB*SSQ/128);     // (8, 256)  V^T GEMM (swapped operands)
  dim3 gq((NB*UU + 127)/128, DM/128);
  dim3 gat(NH, NB, NS);

  conv_bf16<<<gconvW, blk, 0, stream>>>(Wk, Wkb, wN);
  conv_bf16<<<gconvW, blk, 0, stream>>>(Wv, Wvb, wN);
  conv_bf16<<<gconvW, blk, 0, stream>>>(Wq, Wqb, wN);
  conv_bf16<<<gconvW, blk, 0, stream>>>(Wo, Wob, wN);
  gather_q_bf16<<<NB*UU, 128, 0, stream>>>(queries, sidx, Qgb);

  conv_bf16<<<gconvX, blk, 0, stream>>>(keys, Xst, kvE);
  gemm_mfma<true,false><<<gkv, blk, 0, stream>>>(Xst, Wkb, bk, Kbf, NB*SSQ, DM);
  conv_bf16<<<gconvX, blk, 0, stream>>>(values, Xst, kvE);
  gemm_mfma<true,true ><<<gvt, blk, 0, stream>>>(Wvb, Xst, bv, VTb, DM, (long)NB*SSQ);
  gemm_mfma<true,false><<<gq, blk, 0, stream>>>(Qgb, Wqb, bq, Qs16, NB*UU, DM);

  attn_stats<<<gat, blk, 0, stream>>>(Qs16, Kbf, STp);
  merge_stats<<<(NB*NH*UU + 255)/256, blk, 0, stream>>>(STp, ST);
  attn_pv<<<gat, blk, 0, stream>>>(Qs16, Kbf, VTb, ST, attn, ohp);

  reduce_oh<<<((long)NB*UU*DM + 255)/256, blk, 0, stream>>>(ohp, OHb);
  gemm_mfma<false,false><<<gq, blk, 0, stream>>>(OHb, Wob, bo, out_main, NB*UU, DM);
}

// Round 2
// 654.350 us; speedup vs baseline: 1.4673x; 1.2049x over previous
//
#include <hip/hip_runtime.h>
#include <stdint.h>

#define DM  1024
#define NB  8
#define LQ  4096
#define SSQ 4096
#define NH  16
#define HE  64
#define UU  40
#define NS  8
#define SPL (SSQ/NS)

using u16 = unsigned short;
using u32 = unsigned int;

typedef __bf16 bf16x8 __attribute__((ext_vector_type(8)));
typedef float  f32x4  __attribute__((ext_vector_type(4)));

#define AS1 __attribute__((address_space(1)))
#define AS3 __attribute__((address_space(3)))

__device__ __forceinline__ void gld_lds16(const void* g, void* l) {
  __builtin_amdgcn_global_load_lds((const AS1 u32*)g, (AS3 u32*)l, 16, 0, 0);
}

__device__ __forceinline__ u16 f2bf(float x) {
  u32 u = __float_as_uint(x);
  u32 r = (u + 0x7fffu + ((u >> 16) & 1u)) >> 16;   // RNE
  return (u16)r;
}

// ---------------- fp32 -> bf16 convert ------------------------------------
__global__ __launch_bounds__(256)
void conv_bf16(const float* __restrict__ src, u16* __restrict__ dst, long n) {
  long i = ((long)blockIdx.x * 256 + threadIdx.x) * 8;
  if (i >= n) return;
  float4 a = *(const float4*)(src + i);
  float4 b = *(const float4*)(src + i + 4);
  union { u16 h[8]; uint4 v; } pk;
  pk.h[0]=f2bf(a.x); pk.h[1]=f2bf(a.y); pk.h[2]=f2bf(a.z); pk.h[3]=f2bf(a.w);
  pk.h[4]=f2bf(b.x); pk.h[5]=f2bf(b.y); pk.h[6]=f2bf(b.z); pk.h[7]=f2bf(b.w);
  *(uint4*)(dst + i) = pk.v;
}

// fused 4-weight convert (one launch instead of four)
struct WPtrs {
  const float* s0; const float* s1; const float* s2; const float* s3;
  u16* d0; u16* d1; u16* d2; u16* d3;
};
__global__ __launch_bounds__(256)
void conv_w4(WPtrs p) {
  int wsel = blockIdx.y;
  const float* s = wsel==0 ? p.s0 : wsel==1 ? p.s1 : wsel==2 ? p.s2 : p.s3;
  u16*         d = wsel==0 ? p.d0 : wsel==1 ? p.d1 : wsel==2 ? p.d2 : p.d3;
  long i = ((long)blockIdx.x * 256 + threadIdx.x) * 8;
  float4 a = *(const float4*)(s + i);
  float4 b = *(const float4*)(s + i + 4);
  union { u16 h[8]; uint4 v; } pk;
  pk.h[0]=f2bf(a.x); pk.h[1]=f2bf(a.y); pk.h[2]=f2bf(a.z); pk.h[3]=f2bf(a.w);
  pk.h[4]=f2bf(b.x); pk.h[5]=f2bf(b.y); pk.h[6]=f2bf(b.z); pk.h[7]=f2bf(b.w);
  *(uint4*)(d + i) = pk.v;
}

// gather sampled query rows -> contiguous [NB*UU][DM] bf16
__global__ __launch_bounds__(128)
void gather_q_bf16(const float* __restrict__ q, const int* __restrict__ sidx,
                   u16* __restrict__ dst) {
  int r = blockIdx.x;                  // 0..NB*UU-1
  int b = r / UU, u = r - b*UU;
  long srow = ((long)b*LQ + sidx[u]) * DM;
  int c = threadIdx.x * 8;
  float4 a = *(const float4*)(q + srow + c);
  float4 bb = *(const float4*)(q + srow + c + 4);
  union { u16 h[8]; uint4 v; } pk;
  pk.h[0]=f2bf(a.x); pk.h[1]=f2bf(a.y); pk.h[2]=f2bf(a.z); pk.h[3]=f2bf(a.w);
  pk.h[4]=f2bf(bb.x); pk.h[5]=f2bf(bb.y); pk.h[6]=f2bf(bb.z); pk.h[7]=f2bf(bb.w);
  *(uint4*)(dst + (long)r*DM + c) = pk.v;
}

// ============= 256x256 BK=64 double-buffered MFMA GEMM (big shapes) =======
// C[r,c] = sum_k A[r,k]*B[c,k] + bias, A/B bf16 row-major K-contig, K=1024.
// Requires: R%256==0, Ncols%256==0, grid = (R/256)*(N/256) (1-D), %8==0.
// 512 thr / 8 waves (2Mx4N), per-wave 128x64 out. LDS 128 KiB (2 bufs).
// XOR-swizzled LDS (byte ^= (row&7)<<4) via pre-swizzled global source
// (linear gld_lds dest) + swizzled ds_read. Coalesced bf16 epilogue via LDS.
template<bool BIAS_ROW, bool MINOR_N>
__global__ __launch_bounds__(512, 2)
void gemm256(const u16* __restrict__ Ab, const u16* __restrict__ Bb,
             const float* __restrict__ bias, u16* __restrict__ Cb,
             int mTiles, int nTiles, long ldo)
{
  __shared__ u16 lds[2][2][256*64];   // [buf][0=A,1=B][row*64 + swizzled col]
  const int t = threadIdx.x;
  const int l = t & 63;
  const int w = t >> 6;
  const int wr = w >> 2, wc = w & 3;

  // bijective XCD swizzle (nwg % 8 == 0), minor axis fastest for L2 reuse
  const int nwg = mTiles * nTiles;
  const int bid = blockIdx.x;
  const int wg = (bid & 7) * (nwg >> 3) + (bid >> 3);
  int xm, yn;
  if (MINOR_N) { xm = wg / nTiles; yn = wg - xm*nTiles; }
  else         { yn = wg / mTiles; xm = wg - yn*mTiles; }
  const int r0 = xm * 256, o0 = yn * 256;

  // staging: chunk c = t + 512*j ; row=c>>3, slot=c&7, src col16 = slot^(row&7)
  const int srow = t >> 3, sslot = t & 7;
  const int scol = (sslot ^ (srow & 7)) * 8;
  const long aoff = (long)(r0 + srow) * DM + scol;
  const long boff = (long)(o0 + srow) * DM + scol;

  f32x4 acc[8][4];
  const f32x4 z4 = {0.f,0.f,0.f,0.f};
#pragma unroll
  for (int m = 0; m < 8; m++)
#pragma unroll
    for (int n = 0; n < 4; n++) acc[m][n] = z4;

  const int swz   = (l & 7) << 4;      // read-side XOR (row&7)<<4, row&7 == l&7
  const int klane = (l >> 4) << 4;     // byte offset of this lane's 16B k-slice
  const int arow0 = wr*128 + (l & 15);
  const int brow0 = wc*64  + (l & 15);

  auto stage = [&](int tile, int buf) {
#pragma unroll
    for (int j = 0; j < 4; j++)
      gld_lds16(Ab + aoff + (long)j*(64*DM) + tile*64,
                (char*)&lds[buf][0][0] + (512*j + 64*w)*16);
#pragma unroll
    for (int j = 0; j < 4; j++)
      gld_lds16(Bb + boff + (long)j*(64*DM) + tile*64,
                (char*)&lds[buf][1][0] + (512*j + 64*w)*16);
  };

  stage(0, 0);
  __syncthreads();

  for (int tt = 0; tt < 16; tt++) {
    const int cur = tt & 1;
    if (tt < 15) stage(tt+1, cur^1);   // prefetch next tile into other buffer
    const char* Abase = (const char*)&lds[cur][0][0];
    const char* Bbase = (const char*)&lds[cur][1][0];
#pragma unroll
    for (int kk = 0; kk < 2; kk++) {
      const int cb = (kk*64 + klane) ^ swz;
      bf16x8 af[8], bf[4];
#pragma unroll
      for (int m = 0; m < 8; m++)
        af[m] = *(const bf16x8*)(Abase + (arow0 + m*16)*128 + cb);
#pragma unroll
      for (int n = 0; n < 4; n++)
        bf[n] = *(const bf16x8*)(Bbase + (brow0 + n*16)*128 + cb);
      __builtin_amdgcn_s_setprio(1);
#pragma unroll
      for (int m = 0; m < 8; m++)
#pragma unroll
        for (int n = 0; n < 4; n++)
          acc[m][n] = __builtin_amdgcn_mfma_f32_16x16x32_bf16(af[m], bf[n], acc[m][n], 0, 0, 0);
      __builtin_amdgcn_s_setprio(0);
    }
    __syncthreads();   // drains vmcnt (next tile landed) + frees this buffer
  }

  // ---- epilogue: per-wave LDS transpose -> coalesced 16B bf16 stores ----
  float* eps = (float*)((char*)&lds[0][0][0] + w*8704);   // 32 rows x 68 f32
  const int colg = o0 + wc*64 + (l & 7)*8;
  float bc[8];
  if (!BIAS_ROW) {
    float4 b0 = *(const float4*)&bias[colg];
    float4 b1 = *(const float4*)&bias[colg + 4];
    bc[0]=b0.x; bc[1]=b0.y; bc[2]=b0.z; bc[3]=b0.w;
    bc[4]=b1.x; bc[5]=b1.y; bc[6]=b1.z; bc[7]=b1.w;
  }
  const int fq = l >> 4;
  const int fr16 = l & 15;
#pragma unroll
  for (int mc = 0; mc < 4; mc++) {
#pragma unroll
    for (int mm = 0; mm < 2; mm++) {
      int m = mc*2 + mm;
#pragma unroll
      for (int n = 0; n < 4; n++)
#pragma unroll
        for (int i2 = 0; i2 < 4; i2++)
          eps[(mm*16 + fq*4 + i2)*68 + n*16 + fr16] = acc[m][n][i2];
    }
#pragma unroll
    for (int p = 0; p < 4; p++) {
      int lr = p*8 + (l >> 3);
      int rg = r0 + wr*128 + mc*32 + lr;
      const float* sp = &eps[lr*68 + (l & 7)*8];
      float4 v0 = *(const float4*)sp;
      float4 v1 = *(const float4*)(sp + 4);
      float br = BIAS_ROW ? bias[rg] : 0.f;
      float vv[8] = {v0.x,v0.y,v0.z,v0.w,v1.x,v1.y,v1.z,v1.w};
      union { u16 h[8]; uint4 u; } pk;
#pragma unroll
      for (int q2 = 0; q2 < 8; q2++)
        pk.h[q2] = f2bf(vv[q2] + (BIAS_ROW ? br : bc[q2]));
      *(uint4*)&Cb[(long)rg*ldo + colg] = pk.u;
    }
  }
}

// ---------------- small bf16 MFMA GEMM (R=320 paths) ----------------------
template<bool OUT_BF16, bool BIAS_ROW>
__global__ __launch_bounds__(256)
void gemm_mfma(const u16* __restrict__ Xb, const u16* __restrict__ Wb,
               const float* __restrict__ bias, void* __restrict__ outp,
               int R, long ldo)
{
  __shared__ u16 As[128*40];
  __shared__ u16 Bs[128*40];
  const int t = threadIdx.x;
  const int l = t & 63;
  const int w = t >> 6;
  const int r0 = blockIdx.x * 128;
  const int o0 = blockIdx.y * 128;

  const u16* gsrc[5];
  char* ldst[5];
#pragma unroll
  for (int i = 0; i < 5; i++) {
    int c  = i*256 + t;
    int cb = i*256 + w*64;
    bool a = (cb < 640);
    int cc2 = a ? c : (c - 640);
    int row = cc2 / 5, col = cc2 % 5; if (col > 3) col = 0;
    if (a) {
      int rr = r0 + row; if (rr > R-1) rr = R-1;
      gsrc[i] = Xb + (long)rr * DM + col*8;
      ldst[i] = (char*)As + cb*16;
    } else {
      gsrc[i] = Wb + (long)(o0 + row) * DM + col*8;
      ldst[i] = (char*)Bs + (cb - 640)*16;
    }
  }

  f32x4 acc[4][4];
  const f32x4 z4 = {0.f, 0.f, 0.f, 0.f};
#pragma unroll
  for (int mt = 0; mt < 4; mt++)
#pragma unroll
    for (int nt = 0; nt < 4; nt++) acc[mt][nt] = z4;

  const int rw = (w >> 1) * 64;
  const int cw = (w & 1) * 64;
  const int fr = l & 15;
  const int fk = (l >> 4) * 8;

  for (int k0 = 0; k0 < DM; k0 += 32) {
    __syncthreads();
#pragma unroll
    for (int i = 0; i < 5; i++)
      gld_lds16(gsrc[i] + k0, ldst[i]);
    __syncthreads();

    bf16x8 af[4], bf[4];
#pragma unroll
    for (int mt = 0; mt < 4; mt++)
      af[mt] = *(const bf16x8*)&As[(rw + mt*16 + fr)*40 + fk];
#pragma unroll
    for (int nt = 0; nt < 4; nt++)
      bf[nt] = *(const bf16x8*)&Bs[(cw + nt*16 + fr)*40 + fk];
#pragma unroll
    for (int mt = 0; mt < 4; mt++)
#pragma unroll
      for (int nt = 0; nt < 4; nt++)
        acc[mt][nt] = __builtin_amdgcn_mfma_f32_16x16x32_bf16(af[mt], bf[nt], acc[mt][nt], 0, 0, 0);
  }

  const int colBase = o0 + cw + (l & 15);
  const int rowBase = r0 + rw + ((l >> 4) << 2);
#pragma unroll
  for (int nt = 0; nt < 4; nt++) {
    float bvc = BIAS_ROW ? 0.f : bias[colBase + nt*16];
#pragma unroll
    for (int mt = 0; mt < 4; mt++) {
#pragma unroll
      for (int i2 = 0; i2 < 4; i2++) {
        int r = rowBase + mt*16 + i2;
        if (r < R) {
          float v = acc[mt][nt][i2] + (BIAS_ROW ? bias[r] : bvc);
          long o = (long)r*ldo + colBase + nt*16;
          if (OUT_BF16) ((u16*)outp)[o] = f2bf(v);
          else          ((float*)outp)[o] = v;
        }
      }
    }
  }
}

// ---------------- kernel A: MFMA scores -> per-split softmax stats --------
__global__ __launch_bounds__(256)
void attn_stats(const u16* __restrict__ Qs16, const u16* __restrict__ Kb,
                float* __restrict__ STp)
{
  const int h = blockIdx.x, b = blockIdx.y, z = blockIdx.z;
  const int t = threadIdx.x, l = t & 63, w = t >> 6;
  __shared__ float sm4[4][48], sl4[4][48];

  bf16x8 qf[3][2];
#pragma unroll
  for (int mt = 0; mt < 3; mt++) {
    int u = mt*16 + (l & 15); if (u >= UU) u = UU-1;
    const u16* qrow = Qs16 + ((long)b*UU + u)*DM + h*HE + ((l>>4)*8);
    qf[mt][0] = *(const bf16x8*)qrow;
    qf[mt][1] = *(const bf16x8*)(qrow + 32);
  }
  float m_[12], l_[12];
#pragma unroll
  for (int i = 0; i < 12; i++) { m_[i] = -1e30f; l_[i] = 0.f; }

  const f32x4 z4 = {0.f,0.f,0.f,0.f};
  const int sbase = z*SPL + w*128;
  for (int tt = 0; tt < 8; tt++) {
    const int s0 = sbase + tt*16;
    const u16* krow = Kb + ((long)(b*SSQ + s0 + (l & 15)))*DM + h*HE + ((l>>4)*8);
    bf16x8 kf0 = *(const bf16x8*)krow;
    bf16x8 kf1 = *(const bf16x8*)(krow + 32);
    f32x4 as[3];
#pragma unroll
    for (int mt = 0; mt < 3; mt++) {
      as[mt] = __builtin_amdgcn_mfma_f32_16x16x32_bf16(qf[mt][0], kf0, z4, 0, 0, 0);
      as[mt] = __builtin_amdgcn_mfma_f32_16x16x32_bf16(qf[mt][1], kf1, as[mt], 0, 0, 0);
    }
#pragma unroll
    for (int mt = 0; mt < 3; mt++)
#pragma unroll
      for (int i2 = 0; i2 < 4; i2++) {
        int idx = mt*4 + i2;
        float x = as[mt][i2] * 0.03125f;
        float mn = fmaxf(m_[idx], x);
        l_[idx] = l_[idx]*__expf(m_[idx]-mn) + __expf(x-mn);
        m_[idx] = mn;
      }
  }
#pragma unroll
  for (int off = 1; off < 16; off <<= 1)
#pragma unroll
    for (int idx = 0; idx < 12; idx++) {
      float m2 = __shfl_xor(m_[idx], off, 64);
      float l2 = __shfl_xor(l_[idx], off, 64);
      float mn = fmaxf(m_[idx], m2);
      l_[idx] = l_[idx]*__expf(m_[idx]-mn) + l2*__expf(m2-mn);
      m_[idx] = mn;
    }
  if ((l & 15) == 0) {
#pragma unroll
    for (int idx = 0; idx < 12; idx++) {
      int u = (idx>>2)*16 + ((l>>4)<<2) + (idx&3);
      sm4[w][u] = m_[idx]; sl4[w][u] = l_[idx];
    }
  }
  __syncthreads();
  if (t < UU) {
    float M = -1e30f, L = 0.f;
#pragma unroll
    for (int wv = 0; wv < 4; wv++) {
      float m2 = sm4[wv][t], l2 = sl4[wv][t];
      float mn = fmaxf(M, m2);
      L = L*__expf(M-mn) + l2*__expf(m2-mn);
      M = mn;
    }
    long p = (((long)(b*NH + h)*UU + t)*NS + z)*2;
    STp[p] = M; STp[p+1] = L;
  }
}

// ---------------- merge per-split (m,l) -> global (M,L) -------------------
__global__ __launch_bounds__(256)
void merge_stats(const float* __restrict__ STp, float* __restrict__ ST) {
  int idx = blockIdx.x*256 + threadIdx.x;
  if (idx >= NB*NH*UU) return;
  float M = -1e30f;
#pragma unroll
  for (int z = 0; z < NS; z++) M = fmaxf(M, STp[((long)idx*NS+z)*2]);
  float L = 0.f;
#pragma unroll
  for (int z = 0; z < NS; z++)
    L += STp[((long)idx*NS+z)*2+1] * __expf(STp[((long)idx*NS+z)*2] - M);
  ST[idx*2] = M; ST[idx*2+1] = L;
}

// ---------------- kernel B: recompute scores, write attn once, MFMA PV ----
__global__ __launch_bounds__(256, 2)
void attn_pv(const u16* __restrict__ Qs16, const u16* __restrict__ Kb,
             const u16* __restrict__ VTb, const float* __restrict__ ST,
             float* __restrict__ attn, float* __restrict__ ohp)
{
  const int h = blockIdx.x, b = blockIdx.y, z = blockIdx.z;
  const int t = threadIdx.x, l = t & 63, w = t >> 6;
  const long LVT = (long)NB*SSQ;

  __shared__ u16   Plds[4][48*40];
  __shared__ float sM[48], sLi[48];
  __shared__ float red[48][68];

  if (t < 48) {
    if (t < UU) {
      long p = ((long)(b*NH+h)*UU + t)*2;
      sM[t] = ST[p]; sLi[t] = 1.f / ST[p+1];
    } else { sM[t] = 0.f; sLi[t] = 0.f; }
  }
  __syncthreads();

  float Mr[12], Lir[12];
#pragma unroll
  for (int mt = 0; mt < 3; mt++)
#pragma unroll
    for (int i2 = 0; i2 < 4; i2++) {
      int u = mt*16 + ((l>>4)<<2) + i2;
      Mr[mt*4+i2] = sM[u]; Lir[mt*4+i2] = sLi[u];
    }

  bf16x8 qf[3][2];
#pragma unroll
  for (int mt = 0; mt < 3; mt++) {
    int u = mt*16 + (l & 15); if (u >= UU) u = UU-1;
    const u16* qrow = Qs16 + ((long)b*UU + u)*DM + h*HE + ((l>>4)*8);
    qf[mt][0] = *(const bf16x8*)qrow;
    qf[mt][1] = *(const bf16x8*)(qrow + 32);
  }

  f32x4 acc_pv[4][3];
  const f32x4 z4 = {0.f,0.f,0.f,0.f};
#pragma unroll
  for (int et = 0; et < 4; et++)
#pragma unroll
    for (int nt = 0; nt < 3; nt++) acc_pv[et][nt] = z4;

  const int sbase = z*SPL + w*128;
  for (int tt = 0; tt < 4; tt++) {
    const int s0 = sbase + tt*32;
    bf16x8 vf[4];
#pragma unroll
    for (int et = 0; et < 4; et++)
      vf[et] = *(const bf16x8*)(VTb + (long)(h*HE + et*16 + (l&15))*LVT
                                    + (long)b*SSQ + s0 + ((l>>4)*8));
    bf16x8 kf[2][2];
#pragma unroll
    for (int st = 0; st < 2; st++) {
      const u16* krow = Kb + ((long)(b*SSQ + s0 + st*16 + (l & 15)))*DM + h*HE + ((l>>4)*8);
      kf[st][0] = *(const bf16x8*)krow;
      kf[st][1] = *(const bf16x8*)(krow + 32);
    }
#pragma unroll
    for (int st = 0; st < 2; st++) {
      f32x4 as[3];
#pragma unroll
      for (int mt = 0; mt < 3; mt++) {
        as[mt] = __builtin_amdgcn_mfma_f32_16x16x32_bf16(qf[mt][0], kf[st][0], z4, 0, 0, 0);
        as[mt] = __builtin_amdgcn_mfma_f32_16x16x32_bf16(qf[mt][1], kf[st][1], as[mt], 0, 0, 0);
      }
#pragma unroll
      for (int mt = 0; mt < 3; mt++)
#pragma unroll
        for (int i2 = 0; i2 < 4; i2++) {
          int idx = mt*4 + i2;
          int u = mt*16 + ((l>>4)<<2) + i2;
          float p = __expf(as[mt][i2]*0.03125f - Mr[idx]) * Lir[idx];
          if (u < UU)
            attn[((long)((b*NH+h)*UU + u))*SSQ + s0 + st*16 + (l & 15)] = p;
          Plds[w][u*40 + st*16 + (l & 15)] = f2bf(p);
        }
    }
#pragma unroll
    for (int nt = 0; nt < 3; nt++) {
      bf16x8 pb = *(const bf16x8*)&Plds[w][(nt*16 + (l & 15))*40 + ((l>>4)*8)];
#pragma unroll
      for (int et = 0; et < 4; et++)
        acc_pv[et][nt] = __builtin_amdgcn_mfma_f32_16x16x32_bf16(vf[et], pb, acc_pv[et][nt], 0, 0, 0);
    }
  }

  __syncthreads();
  for (int wv = 0; wv < 4; wv++) {
    if (w == wv) {
#pragma unroll
      for (int et = 0; et < 4; et++)
#pragma unroll
        for (int nt = 0; nt < 3; nt++)
#pragma unroll
          for (int i2 = 0; i2 < 4; i2++) {
            int u = nt*16 + (l & 15);
            int e = et*16 + ((l>>4)<<2) + i2;
            if (wv == 0) red[u][e]  = acc_pv[et][nt][i2];
            else         red[u][e] += acc_pv[et][nt][i2];
          }
    }
    __syncthreads();
  }
  for (int idx = t; idx < UU*64; idx += 256) {
    int u = idx >> 6, e = idx & 63;
    ohp[(long)z*((long)NB*UU*DM) + ((long)b*UU + u)*DM + h*HE + e] = red[u][e];
  }
}

// ---------------- reduce PV partials -> bf16 OH ---------------------------
__global__ __launch_bounds__(256)
void reduce_oh(const float* __restrict__ ohp, u16* __restrict__ ohb) {
  long i = (long)blockIdx.x*256 + threadIdx.x;
  const long n = (long)NB*UU*DM;
  if (i >= n) return;
  float s = 0.f;
#pragma unroll
  for (int z = 0; z < NS; z++) s += ohp[(long)z*n + i];
  ohb[i] = f2bf(s);
}

extern "C" void kernel_launch(void* const* d_in, const int* in_sizes, int n_in,
                              void* d_out, int out_size, void* d_ws, size_t ws_size,
                              hipStream_t stream)
{
  const float* queries = (const float*)d_in[0];
  const float* keys    = (const float*)d_in[1];
  const float* values  = (const float*)d_in[2];
  const float* Wq = (const float*)d_in[3];
  const float* bq = (const float*)d_in[4];
  const float* Wk = (const float*)d_in[5];
  const float* bk = (const float*)d_in[6];
  const float* Wv = (const float*)d_in[7];
  const float* bv = (const float*)d_in[8];
  const float* Wo = (const float*)d_in[9];
  const float* bo = (const float*)d_in[10];
  const int* sidx = (const int*)d_in[11];

  float* out_main = (float*)d_out;
  float* attn     = out_main + (long)NB*UU*DM;

  const long kvE = (long)NB*SSQ*DM;         // 33,554,432
  const size_t wB = (size_t)DM*DM*2;        // one bf16 weight

  char* ws = (char*)d_ws;
  u16*  Xst = (u16*)ws;                      ws += (size_t)kvE*2;   // bf16 staged input
  u16*  Kbf = (u16*)ws;                      ws += (size_t)kvE*2;   // K bf16 [b*S+s][DM]
  u16*  VTb = (u16*)ws;                      ws += (size_t)kvE*2;   // V^T bf16 [o][b*S+s]
  u16*  Wkb = (u16*)ws;                      ws += wB;
  u16*  Wvb = (u16*)ws;                      ws += wB;
  u16*  Wqb = (u16*)ws;                      ws += wB;
  u16*  Wob = (u16*)ws;                      ws += wB;
  u16*  Qgb = (u16*)ws;                      ws += (size_t)NB*UU*DM*2;
  u16*  Qs16= (u16*)ws;                      ws += (size_t)NB*UU*DM*2;
  u16*  OHb = (u16*)ws;                      ws += (size_t)NB*UU*DM*2;
  float* ohp = (float*)ws;                   ws += (size_t)NS*NB*UU*DM*4;
  float* STp = (float*)ws;                   ws += (size_t)NB*NH*UU*NS*2*4;
  float* ST  = (float*)ws;

  dim3 blk(256);
  const long wN = (long)DM*DM;
  dim3 gconvX((kvE/8 + 255)/256);
  dim3 gw4(wN/8/256, 4);            // (512, 4) fused weight convert
  dim3 gq((NB*UU + 127)/128, DM/128);
  dim3 gat(NH, NB, NS);

  WPtrs wp = { Wk, Wv, Wq, Wo, Wkb, Wvb, Wqb, Wob };
  conv_w4<<<gw4, blk, 0, stream>>>(wp);
  gather_q_bf16<<<NB*UU, 128, 0, stream>>>(queries, sidx, Qgb);

  // K = keys*Wk^T + bk -> bf16 [b*S+s][DM]; grid 128x4 tiles, N minor
  conv_bf16<<<gconvX, blk, 0, stream>>>(keys, Xst, kvE);
  gemm256<false,true><<<dim3(512), dim3(512), 0, stream>>>(Xst, Wkb, bk, Kbf,
                                                           128, 4, (long)DM);
  // V^T = Wv*values^T + bv(row) -> bf16 [o][b*S+s]; grid 4x128 tiles, M minor
  conv_bf16<<<gconvX, blk, 0, stream>>>(values, Xst, kvE);
  gemm256<true,false><<<dim3(512), dim3(512), 0, stream>>>(Wvb, Xst, bv, VTb,
                                                           4, 128, (long)NB*SSQ);
  // Qs (sampled rows) -> bf16 (small GEMM path)
  gemm_mfma<true,false><<<gq, blk, 0, stream>>>(Qgb, Wqb, bq, Qs16, NB*UU, DM);

  attn_stats<<<gat, blk, 0, stream>>>(Qs16, Kbf, STp);
  merge_stats<<<(NB*NH*UU + 255)/256, blk, 0, stream>>>(STp, ST);
  attn_pv<<<gat, blk, 0, stream>>>(Qs16, Kbf, VTb, ST, attn, ohp);

  reduce_oh<<<((long)NB*UU*DM + 255)/256, blk, 0, stream>>>(ohp, OHb);
  gemm_mfma<false,false><<<gq, blk, 0, stream>>>(OHb, Wob, bo, out_main, NB*UU, DM);
}

// Round 3
// 624.100 us; speedup vs baseline: 1.5384x; 1.0485x over previous
//
#include <hip/hip_runtime.h>
#include <stdint.h>

#define DM  1024
#define NB  8
#define LQ  4096
#define SSQ 4096
#define NH  16
#define HE  64
#define UU  40
#define NS  8
#define SPL (SSQ/NS)
#define KS  4            // split-K factor for small GEMMs

using u16 = unsigned short;
using u32 = unsigned int;

typedef __bf16 bf16x8 __attribute__((ext_vector_type(8)));
typedef float  f32x4  __attribute__((ext_vector_type(4)));

#define AS1 __attribute__((address_space(1)))
#define AS3 __attribute__((address_space(3)))

__device__ __forceinline__ void gld_lds16(const void* g, void* l) {
  __builtin_amdgcn_global_load_lds((const AS1 u32*)g, (AS3 u32*)l, 16, 0, 0);
}

__device__ __forceinline__ u16 f2bf(float x) {
  u32 u = __float_as_uint(x);
  u32 r = (u + 0x7fffu + ((u >> 16) & 1u)) >> 16;   // RNE
  return (u16)r;
}

// fused 4-weight fp32->bf16 convert (one launch)
struct WPtrs {
  const float* s0; const float* s1; const float* s2; const float* s3;
  u16* d0; u16* d1; u16* d2; u16* d3;
};
__global__ __launch_bounds__(256)
void conv_w4(WPtrs p) {
  int wsel = blockIdx.y;
  const float* s = wsel==0 ? p.s0 : wsel==1 ? p.s1 : wsel==2 ? p.s2 : p.s3;
  u16*         d = wsel==0 ? p.d0 : wsel==1 ? p.d1 : wsel==2 ? p.d2 : p.d3;
  long i = ((long)blockIdx.x * 256 + threadIdx.x) * 8;
  float4 a = *(const float4*)(s + i);
  float4 b = *(const float4*)(s + i + 4);
  union { u16 h[8]; uint4 v; } pk;
  pk.h[0]=f2bf(a.x); pk.h[1]=f2bf(a.y); pk.h[2]=f2bf(a.z); pk.h[3]=f2bf(a.w);
  pk.h[4]=f2bf(b.x); pk.h[5]=f2bf(b.y); pk.h[6]=f2bf(b.z); pk.h[7]=f2bf(b.w);
  *(uint4*)(d + i) = pk.v;
}

// gather sampled query rows -> contiguous [NB*UU][DM] bf16
__global__ __launch_bounds__(128)
void gather_q_bf16(const float* __restrict__ q, const int* __restrict__ sidx,
                   u16* __restrict__ dst) {
  int r = blockIdx.x;                  // 0..NB*UU-1
  int b = r / UU, u = r - b*UU;
  long srow = ((long)b*LQ + sidx[u]) * DM;
  int c = threadIdx.x * 8;
  float4 a = *(const float4*)(q + srow + c);
  float4 bb = *(const float4*)(q + srow + c + 4);
  union { u16 h[8]; uint4 v; } pk;
  pk.h[0]=f2bf(a.x); pk.h[1]=f2bf(a.y); pk.h[2]=f2bf(a.z); pk.h[3]=f2bf(a.w);
  pk.h[4]=f2bf(bb.x); pk.h[5]=f2bf(bb.y); pk.h[6]=f2bf(bb.z); pk.h[7]=f2bf(bb.w);
  *(uint4*)(dst + (long)r*DM + c) = pk.v;
}

// ============= 256x256 BK=64 double-buffered MFMA GEMM ====================
// C[r,c] = sum_k A[r,k]*B[c,k] + bias; K=1024; bf16 output.
// A32/B32: that operand is fp32 in global, reg-staged with in-flight bf16
// convert + swizzled ds_write (saves the separate convert pass). The bf16
// operand stages via global_load_lds (linear dest, pre-swizzled source).
// LDS invariant both paths: slot q of row r holds source k-slot q^(r&7).
// 512 thr / 8 waves (2Mx4N), per-wave 128x64 out. LDS 128 KiB (2 bufs).
template<bool A32, bool B32, bool BIAS_ROW, bool MINOR_N>
__global__ __launch_bounds__(512, 2)
void gemm256(const void* __restrict__ Ap, const void* __restrict__ Bp,
             const float* __restrict__ bias, u16* __restrict__ Cb,
             int mTiles, int nTiles, long ldo)
{
  __shared__ u16 lds[2][2][256*64];   // [buf][0=A,1=B][row*64 + slot*8]
  const int t = threadIdx.x;
  const int l = t & 63;
  const int w = t >> 6;
  const int wr = w >> 2, wc = w & 3;

  // bijective XCD swizzle (nwg % 8 == 0), minor axis fastest for L2 reuse
  const int nwg = mTiles * nTiles;
  const int bid = blockIdx.x;
  const int wg = (bid & 7) * (nwg >> 3) + (bid >> 3);
  int xm, yn;
  if (MINOR_N) { xm = wg / nTiles; yn = wg - xm*nTiles; }
  else         { yn = wg / mTiles; xm = wg - yn*mTiles; }
  const int r0 = xm * 256, o0 = yn * 256;

  // staging geometry: chunk c = t + 512*j ; row=c>>3, slot=c&7
  const int srow = t >> 3, sslot = t & 7;
  const int scol  = (sslot ^ (srow & 7)) * 8;   // pre-swizzled src col (gld path)
  const int dslot = (sslot ^ (srow & 7));       // swizzled LDS slot (reg path)

  const u16*   Ab  = (const u16*)Ap   + (long)r0*DM;
  const u16*   Bb  = (const u16*)Bp   + (long)o0*DM;
  const float* Af  = (const float*)Ap + (long)r0*DM;
  const float* Bf  = (const float*)Bp + (long)o0*DM;

  float4 vs[8];   // reg-stage buffer for the fp32 operand
  auto loadS = [&](const float* S, int tile) {
#pragma unroll
    for (int j = 0; j < 4; j++) {
      const float* p = S + (long)(srow + 64*j)*DM + tile*64 + sslot*8;
      vs[2*j]   = *(const float4*)p;
      vs[2*j+1] = *(const float4*)(p + 4);
    }
  };
  auto writeS = [&](int op, int buf) {
#pragma unroll
    for (int j = 0; j < 4; j++) {
      float f[8] = {vs[2*j].x, vs[2*j].y, vs[2*j].z, vs[2*j].w,
                    vs[2*j+1].x, vs[2*j+1].y, vs[2*j+1].z, vs[2*j+1].w};
      union { u16 h[8]; uint4 u4; } pk;
#pragma unroll
      for (int q = 0; q < 8; q++) pk.h[q] = f2bf(f[q]);
      *(uint4*)&lds[buf][op][(srow + 64*j)*64 + dslot*8] = pk.u4;
    }
  };
  auto stageGld = [&](const u16* S, int op, int tile, int buf) {
#pragma unroll
    for (int j = 0; j < 4; j++)
      gld_lds16(S + (long)(srow + 64*j)*DM + tile*64 + scol - (long)(t>>3)*DM
                  + (long)(t>>3)*DM,                     // (srow==t>>3; keep simple)
                (char*)&lds[buf][op][0] + (512*j + 64*w)*16);
  };

  f32x4 acc[8][4];
  const f32x4 z4 = {0.f,0.f,0.f,0.f};
#pragma unroll
  for (int m = 0; m < 8; m++)
#pragma unroll
    for (int n = 0; n < 4; n++) acc[m][n] = z4;

  const int swz   = (l & 7) << 4;      // read-side XOR (row&7)<<4
  const int klane = (l >> 4) << 4;     // byte offset of lane's 16B k-slice
  const int arow0 = wr*128 + (l & 15);
  const int brow0 = wc*64  + (l & 15);

  // ---- prologue: tile 0 into buf 0
  if (A32) loadS(Af, 0);
  if (B32) loadS(Bf, 0);
  if (!A32) stageGld(Ab, 0, 0, 0);
  if (!B32) stageGld(Bb, 1, 0, 0);
  if (A32) writeS(0, 0);
  if (B32) writeS(1, 0);
  __syncthreads();

  for (int tt = 0; tt < 16; tt++) {
    const int cur = tt & 1;
    if (tt < 15) {                      // prefetch next tile
      if (A32) loadS(Af, tt+1);
      if (B32) loadS(Bf, tt+1);
      if (!A32) stageGld(Ab, 0, tt+1, cur^1);
      if (!B32) stageGld(Bb, 1, tt+1, cur^1);
    }
    const char* Abase = (const char*)&lds[cur][0][0];
    const char* Bbase = (const char*)&lds[cur][1][0];
#pragma unroll
    for (int kk = 0; kk < 2; kk++) {
      const int cb = (kk*64 + klane) ^ swz;
      bf16x8 af[8], bf[4];
#pragma unroll
      for (int m = 0; m < 8; m++)
        af[m] = *(const bf16x8*)(Abase + (arow0 + m*16)*128 + cb);
#pragma unroll
      for (int n = 0; n < 4; n++)
        bf[n] = *(const bf16x8*)(Bbase + (brow0 + n*16)*128 + cb);
      __builtin_amdgcn_s_setprio(1);
#pragma unroll
      for (int m = 0; m < 8; m++)
#pragma unroll
        for (int n = 0; n < 4; n++)
          acc[m][n] = __builtin_amdgcn_mfma_f32_16x16x32_bf16(af[m], bf[n], acc[m][n], 0, 0, 0);
      __builtin_amdgcn_s_setprio(0);
    }
    if (tt < 15) {
      if (A32) writeS(0, cur^1);
      if (B32) writeS(1, cur^1);
    }
    __syncthreads();
  }

  // ---- epilogue: per-wave LDS transpose -> coalesced 16B bf16 stores ----
  float* eps = (float*)((char*)&lds[0][0][0] + w*8704);   // 32 rows x 68 f32
  const int colg = o0 + wc*64 + (l & 7)*8;
  float bc[8];
  if (!BIAS_ROW) {
    float4 b0 = *(const float4*)&bias[colg];
    float4 b1 = *(const float4*)&bias[colg + 4];
    bc[0]=b0.x; bc[1]=b0.y; bc[2]=b0.z; bc[3]=b0.w;
    bc[4]=b1.x; bc[5]=b1.y; bc[6]=b1.z; bc[7]=b1.w;
  }
  const int fq = l >> 4;
  const int fr16 = l & 15;
#pragma unroll
  for (int mc = 0; mc < 4; mc++) {
#pragma unroll
    for (int mm = 0; mm < 2; mm++) {
      int m = mc*2 + mm;
#pragma unroll
      for (int n = 0; n < 4; n++)
#pragma unroll
        for (int i2 = 0; i2 < 4; i2++)
          eps[(mm*16 + fq*4 + i2)*68 + n*16 + fr16] = acc[m][n][i2];
    }
#pragma unroll
    for (int p = 0; p < 4; p++) {
      int lr = p*8 + (l >> 3);
      int rg = r0 + wr*128 + mc*32 + lr;
      const float* sp = &eps[lr*68 + (l & 7)*8];
      float4 v0 = *(const float4*)sp;
      float4 v1 = *(const float4*)(sp + 4);
      float br = BIAS_ROW ? bias[rg] : 0.f;
      float vv[8] = {v0.x,v0.y,v0.z,v0.w,v1.x,v1.y,v1.z,v1.w};
      union { u16 h[8]; uint4 u4; } pk;
#pragma unroll
      for (int q2 = 0; q2 < 8; q2++)
        pk.h[q2] = f2bf(vv[q2] + (BIAS_ROW ? br : bc[q2]));
      *(uint4*)&Cb[(long)rg*ldo + colg] = pk.u4;
    }
  }
}

// ---------------- small GEMM, split-K: partial[z][r][c] = sum_k(256) ------
// grid (ceil(R/128), DM/128, KS); 128x128 tile, BK=32, 4 waves.
__global__ __launch_bounds__(256)
void gemm_small_sk(const u16* __restrict__ Xb, const u16* __restrict__ Wb,
                   float* __restrict__ pout, int R)
{
  __shared__ u16 As[128*40];
  __shared__ u16 Bs[128*40];
  const int t = threadIdx.x;
  const int l = t & 63;
  const int w = t >> 6;
  const int r0 = blockIdx.x * 128;
  const int o0 = blockIdx.y * 128;
  const int kz = blockIdx.z;

  const u16* gsrc[5];
  char* ldst[5];
#pragma unroll
  for (int i = 0; i < 5; i++) {
    int c  = i*256 + t;
    int cb = i*256 + w*64;
    bool a = (cb < 640);
    int cc2 = a ? c : (c - 640);
    int row = cc2 / 5, col = cc2 % 5; if (col > 3) col = 0;
    if (a) {
      int rr = r0 + row; if (rr > R-1) rr = R-1;
      gsrc[i] = Xb + (long)rr * DM + col*8;
      ldst[i] = (char*)As + cb*16;
    } else {
      gsrc[i] = Wb + (long)(o0 + row) * DM + col*8;
      ldst[i] = (char*)Bs + (cb - 640)*16;
    }
  }

  f32x4 acc[4][4];
  const f32x4 z4 = {0.f, 0.f, 0.f, 0.f};
#pragma unroll
  for (int mt = 0; mt < 4; mt++)
#pragma unroll
    for (int nt = 0; nt < 4; nt++) acc[mt][nt] = z4;

  const int rw = (w >> 1) * 64;
  const int cw = (w & 1) * 64;
  const int fr = l & 15;
  const int fk = (l >> 4) * 8;

  for (int k0 = kz*(DM/KS); k0 < (kz+1)*(DM/KS); k0 += 32) {
    __syncthreads();
#pragma unroll
    for (int i = 0; i < 5; i++)
      gld_lds16(gsrc[i] + k0, ldst[i]);
    __syncthreads();

    bf16x8 af[4], bf[4];
#pragma unroll
    for (int mt = 0; mt < 4; mt++)
      af[mt] = *(const bf16x8*)&As[(rw + mt*16 + fr)*40 + fk];
#pragma unroll
    for (int nt = 0; nt < 4; nt++)
      bf[nt] = *(const bf16x8*)&Bs[(cw + nt*16 + fr)*40 + fk];
#pragma unroll
    for (int mt = 0; mt < 4; mt++)
#pragma unroll
      for (int nt = 0; nt < 4; nt++)
        acc[mt][nt] = __builtin_amdgcn_mfma_f32_16x16x32_bf16(af[mt], bf[nt], acc[mt][nt], 0, 0, 0);
  }

  const int colBase = o0 + cw + (l & 15);
  const int rowBase = r0 + rw + ((l >> 4) << 2);
  float* pz = pout + (long)kz*R*DM;
#pragma unroll
  for (int nt = 0; nt < 4; nt++)
#pragma unroll
    for (int mt = 0; mt < 4; mt++)
#pragma unroll
      for (int i2 = 0; i2 < 4; i2++) {
        int r = rowBase + mt*16 + i2;
        if (r < R) pz[(long)r*DM + colBase + nt*16] = acc[mt][nt][i2];
      }
}

// combine split-K partials + bias(col)
template<bool OUT_BF16>
__global__ __launch_bounds__(256)
void combine_sk(const float* __restrict__ p, const float* __restrict__ bias,
                void* __restrict__ out, int R)
{
  long n = (long)R*DM;
  long i = (long)blockIdx.x*256 + threadIdx.x;
  if (i >= n) return;
  float s = bias[i & (DM-1)];
#pragma unroll
  for (int z = 0; z < KS; z++) s += p[(long)z*n + i];
  if (OUT_BF16) ((u16*)out)[i] = f2bf(s);
  else          ((float*)out)[i] = s;
}

// ---------------- kernel A: MFMA scores -> per-split softmax stats --------
__global__ __launch_bounds__(256)
void attn_stats(const u16* __restrict__ Qs16, const u16* __restrict__ Kb,
                float* __restrict__ STp)
{
  const int h = blockIdx.x, b = blockIdx.y, z = blockIdx.z;
  const int t = threadIdx.x, l = t & 63, w = t >> 6;
  __shared__ float sm4[4][48], sl4[4][48];

  bf16x8 qf[3][2];
#pragma unroll
  for (int mt = 0; mt < 3; mt++) {
    int u = mt*16 + (l & 15); if (u >= UU) u = UU-1;
    const u16* qrow = Qs16 + ((long)b*UU + u)*DM + h*HE + ((l>>4)*8);
    qf[mt][0] = *(const bf16x8*)qrow;
    qf[mt][1] = *(const bf16x8*)(qrow + 32);
  }
  float m_[12], l_[12];
#pragma unroll
  for (int i = 0; i < 12; i++) { m_[i] = -1e30f; l_[i] = 0.f; }

  const f32x4 z4 = {0.f,0.f,0.f,0.f};
  const int sbase = z*SPL + w*128;
  for (int tt = 0; tt < 8; tt++) {
    const int s0 = sbase + tt*16;
    const u16* krow = Kb + ((long)(b*SSQ + s0 + (l & 15)))*DM + h*HE + ((l>>4)*8);
    bf16x8 kf0 = *(const bf16x8*)krow;
    bf16x8 kf1 = *(const bf16x8*)(krow + 32);
    f32x4 as[3];
#pragma unroll
    for (int mt = 0; mt < 3; mt++) {
      as[mt] = __builtin_amdgcn_mfma_f32_16x16x32_bf16(qf[mt][0], kf0, z4, 0, 0, 0);
      as[mt] = __builtin_amdgcn_mfma_f32_16x16x32_bf16(qf[mt][1], kf1, as[mt], 0, 0, 0);
    }
#pragma unroll
    for (int mt = 0; mt < 3; mt++)
#pragma unroll
      for (int i2 = 0; i2 < 4; i2++) {
        int idx = mt*4 + i2;
        float x = as[mt][i2] * 0.03125f;
        float mn = fmaxf(m_[idx], x);
        l_[idx] = l_[idx]*__expf(m_[idx]-mn) + __expf(x-mn);
        m_[idx] = mn;
      }
  }
#pragma unroll
  for (int off = 1; off < 16; off <<= 1)
#pragma unroll
    for (int idx = 0; idx < 12; idx++) {
      float m2 = __shfl_xor(m_[idx], off, 64);
      float l2 = __shfl_xor(l_[idx], off, 64);
      float mn = fmaxf(m_[idx], m2);
      l_[idx] = l_[idx]*__expf(m_[idx]-mn) + l2*__expf(m2-mn);
      m_[idx] = mn;
    }
  if ((l & 15) == 0) {
#pragma unroll
    for (int idx = 0; idx < 12; idx++) {
      int u = (idx>>2)*16 + ((l>>4)<<2) + (idx&3);
      sm4[w][u] = m_[idx]; sl4[w][u] = l_[idx];
    }
  }
  __syncthreads();
  if (t < UU) {
    float M = -1e30f, L = 0.f;
#pragma unroll
    for (int wv = 0; wv < 4; wv++) {
      float m2 = sm4[wv][t], l2 = sl4[wv][t];
      float mn = fmaxf(M, m2);
      L = L*__expf(M-mn) + l2*__expf(m2-mn);
      M = mn;
    }
    long p = (((long)(b*NH + h)*UU + t)*NS + z)*2;
    STp[p] = M; STp[p+1] = L;
  }
}

// ---------------- merge per-split (m,l) -> global (M,L) -------------------
__global__ __launch_bounds__(256)
void merge_stats(const float* __restrict__ STp, float* __restrict__ ST) {
  int idx = blockIdx.x*256 + threadIdx.x;
  if (idx >= NB*NH*UU) return;
  float M = -1e30f;
#pragma unroll
  for (int z = 0; z < NS; z++) M = fmaxf(M, STp[((long)idx*NS+z)*2]);
  float L = 0.f;
#pragma unroll
  for (int z = 0; z < NS; z++)
    L += STp[((long)idx*NS+z)*2+1] * __expf(STp[((long)idx*NS+z)*2] - M);
  ST[idx*2] = M; ST[idx*2+1] = L;
}

// ---------------- kernel B: recompute scores, write attn once, MFMA PV ----
__global__ __launch_bounds__(256, 2)
void attn_pv(const u16* __restrict__ Qs16, const u16* __restrict__ Kb,
             const u16* __restrict__ VTb, const float* __restrict__ ST,
             float* __restrict__ attn, float* __restrict__ ohp)
{
  const int h = blockIdx.x, b = blockIdx.y, z = blockIdx.z;
  const int t = threadIdx.x, l = t & 63, w = t >> 6;
  const long LVT = (long)NB*SSQ;

  __shared__ u16   Plds[4][48*40];
  __shared__ float sM[48], sLi[48];
  __shared__ float red[48][68];

  if (t < 48) {
    if (t < UU) {
      long p = ((long)(b*NH+h)*UU + t)*2;
      sM[t] = ST[p]; sLi[t] = 1.f / ST[p+1];
    } else { sM[t] = 0.f; sLi[t] = 0.f; }
  }
  __syncthreads();

  float Mr[12], Lir[12];
#pragma unroll
  for (int mt = 0; mt < 3; mt++)
#pragma unroll
    for (int i2 = 0; i2 < 4; i2++) {
      int u = mt*16 + ((l>>4)<<2) + i2;
      Mr[mt*4+i2] = sM[u]; Lir[mt*4+i2] = sLi[u];
    }

  bf16x8 qf[3][2];
#pragma unroll
  for (int mt = 0; mt < 3; mt++) {
    int u = mt*16 + (l & 15); if (u >= UU) u = UU-1;
    const u16* qrow = Qs16 + ((long)b*UU + u)*DM + h*HE + ((l>>4)*8);
    qf[mt][0] = *(const bf16x8*)qrow;
    qf[mt][1] = *(const bf16x8*)(qrow + 32);
  }

  f32x4 acc_pv[4][3];
  const f32x4 z4 = {0.f,0.f,0.f,0.f};
#pragma unroll
  for (int et = 0; et < 4; et++)
#pragma unroll
    for (int nt = 0; nt < 3; nt++) acc_pv[et][nt] = z4;

  const int sbase = z*SPL + w*128;
  for (int tt = 0; tt < 4; tt++) {
    const int s0 = sbase + tt*32;
    bf16x8 vf[4];
#pragma unroll
    for (int et = 0; et < 4; et++)
      vf[et] = *(const bf16x8*)(VTb + (long)(h*HE + et*16 + (l&15))*LVT
                                    + (long)b*SSQ + s0 + ((l>>4)*8));
    bf16x8 kf[2][2];
#pragma unroll
    for (int st = 0; st < 2; st++) {
      const u16* krow = Kb + ((long)(b*SSQ + s0 + st*16 + (l & 15)))*DM + h*HE + ((l>>4)*8);
      kf[st][0] = *(const bf16x8*)krow;
      kf[st][1] = *(const bf16x8*)(krow + 32);
    }
#pragma unroll
    for (int st = 0; st < 2; st++) {
      f32x4 as[3];
#pragma unroll
      for (int mt = 0; mt < 3; mt++) {
        as[mt] = __builtin_amdgcn_mfma_f32_16x16x32_bf16(qf[mt][0], kf[st][0], z4, 0, 0, 0);
        as[mt] = __builtin_amdgcn_mfma_f32_16x16x32_bf16(qf[mt][1], kf[st][1], as[mt], 0, 0, 0);
      }
#pragma unroll
      for (int mt = 0; mt < 3; mt++)
#pragma unroll
        for (int i2 = 0; i2 < 4; i2++) {
          int idx = mt*4 + i2;
          int u = mt*16 + ((l>>4)<<2) + i2;
          float p = __expf(as[mt][i2]*0.03125f - Mr[idx]) * Lir[idx];
          if (u < UU)
            attn[((long)((b*NH+h)*UU + u))*SSQ + s0 + st*16 + (l & 15)] = p;
          Plds[w][u*40 + st*16 + (l & 15)] = f2bf(p);
        }
    }
#pragma unroll
    for (int nt = 0; nt < 3; nt++) {
      bf16x8 pb = *(const bf16x8*)&Plds[w][(nt*16 + (l & 15))*40 + ((l>>4)*8)];
#pragma unroll
      for (int et = 0; et < 4; et++)
        acc_pv[et][nt] = __builtin_amdgcn_mfma_f32_16x16x32_bf16(vf[et], pb, acc_pv[et][nt], 0, 0, 0);
    }
  }

  __syncthreads();
  for (int wv = 0; wv < 4; wv++) {
    if (w == wv) {
#pragma unroll
      for (int et = 0; et < 4; et++)
#pragma unroll
        for (int nt = 0; nt < 3; nt++)
#pragma unroll
          for (int i2 = 0; i2 < 4; i2++) {
            int u = nt*16 + (l & 15);
            int e = et*16 + ((l>>4)<<2) + i2;
            if (wv == 0) red[u][e]  = acc_pv[et][nt][i2];
            else         red[u][e] += acc_pv[et][nt][i2];
          }
    }
    __syncthreads();
  }
  for (int idx = t; idx < UU*64; idx += 256) {
    int u = idx >> 6, e = idx & 63;
    ohp[(long)z*((long)NB*UU*DM) + ((long)b*UU + u)*DM + h*HE + e] = red[u][e];
  }
}

// ---------------- reduce PV partials -> bf16 OH ---------------------------
__global__ __launch_bounds__(256)
void reduce_oh(const float* __restrict__ ohp, u16* __restrict__ ohb) {
  long i = (long)blockIdx.x*256 + threadIdx.x;
  const long n = (long)NB*UU*DM;
  if (i >= n) return;
  float s = 0.f;
#pragma unroll
  for (int z = 0; z < NS; z++) s += ohp[(long)z*n + i];
  ohb[i] = f2bf(s);
}

extern "C" void kernel_launch(void* const* d_in, const int* in_sizes, int n_in,
                              void* d_out, int out_size, void* d_ws, size_t ws_size,
                              hipStream_t stream)
{
  const float* queries = (const float*)d_in[0];
  const float* keys    = (const float*)d_in[1];
  const float* values  = (const float*)d_in[2];
  const float* Wq = (const float*)d_in[3];
  const float* bq = (const float*)d_in[4];
  const float* Wk = (const float*)d_in[5];
  const float* bk = (const float*)d_in[6];
  const float* Wv = (const float*)d_in[7];
  const float* bv = (const float*)d_in[8];
  const float* Wo = (const float*)d_in[9];
  const float* bo = (const float*)d_in[10];
  const int* sidx = (const int*)d_in[11];

  float* out_main = (float*)d_out;
  float* attn     = out_main + (long)NB*UU*DM;

  const long kvE = (long)NB*SSQ*DM;         // 33,554,432
  const size_t wB = (size_t)DM*DM*2;        // one bf16 weight
  const int  RQ = NB*UU;                    // 320

  char* ws = (char*)d_ws;
  u16*  Kbf = (u16*)ws;                      ws += (size_t)kvE*2;   // K bf16 [b*S+s][DM]
  u16*  VTb = (u16*)ws;                      ws += (size_t)kvE*2;   // V^T bf16 [o][b*S+s]
  u16*  Wkb = (u16*)ws;                      ws += wB;
  u16*  Wvb = (u16*)ws;                      ws += wB;
  u16*  Wqb = (u16*)ws;                      ws += wB;
  u16*  Wob = (u16*)ws;                      ws += wB;
  u16*  Qgb = (u16*)ws;                      ws += (size_t)RQ*DM*2;
  u16*  Qs16= (u16*)ws;                      ws += (size_t)RQ*DM*2;
  u16*  OHb = (u16*)ws;                      ws += (size_t)RQ*DM*2;
  float* pbuf= (float*)ws;                   ws += (size_t)KS*RQ*DM*4;
  float* ohp = (float*)ws;                   ws += (size_t)NS*NB*UU*DM*4;
  float* STp = (float*)ws;                   ws += (size_t)NB*NH*UU*NS*2*4;
  float* ST  = (float*)ws;

  dim3 blk(256);
  const long wN = (long)DM*DM;
  dim3 gw4(wN/8/256, 4);            // (512, 4) fused weight convert
  dim3 gsk((RQ + 127)/128, DM/128, KS);
  dim3 gcmb(((long)RQ*DM + 255)/256);
  dim3 gat(NH, NB, NS);

  WPtrs wp = { Wk, Wv, Wq, Wo, Wkb, Wvb, Wqb, Wob };
  conv_w4<<<gw4, blk, 0, stream>>>(wp);
  gather_q_bf16<<<RQ, 128, 0, stream>>>(queries, sidx, Qgb);

  // K = keys*Wk^T + bk -> bf16 [b*S+s][DM]; A = keys fp32 (fused convert)
  gemm256<true,false,false,true><<<dim3(512), dim3(512), 0, stream>>>(
      keys, Wkb, bk, Kbf, 128, 4, (long)DM);
  // V^T = Wv*values^T + bv(row) -> bf16 [o][b*S+s]; B = values fp32 (fused)
  gemm256<false,true,true,false><<<dim3(512), dim3(512), 0, stream>>>(
      Wvb, values, bv, VTb, 4, 128, (long)NB*SSQ);

  // Qs (sampled rows) -> bf16, split-K
  gemm_small_sk<<<gsk, blk, 0, stream>>>(Qgb, Wqb, pbuf, RQ);
  combine_sk<true><<<gcmb, blk, 0, stream>>>(pbuf, bq, Qs16, RQ);

  attn_stats<<<gat, blk, 0, stream>>>(Qs16, Kbf, STp);
  merge_stats<<<(NB*NH*UU + 255)/256, blk, 0, stream>>>(STp, ST);
  attn_pv<<<gat, blk, 0, stream>>>(Qs16, Kbf, VTb, ST, attn, ohp);

  reduce_oh<<<((long)NB*UU*DM + 255)/256, blk, 0, stream>>>(ohp, OHb);

  // out = OH*Wo^T + bo (fp32), split-K
  gemm_small_sk<<<gsk, blk, 0, stream>>>(OHb, Wob, pbuf, RQ);
  combine_sk<false><<<gcmb, blk, 0, stream>>>(pbuf, bo, out_main, RQ);
}